// Round 3
// baseline (699.084 us; speedup 1.0000x reference)
//
#include <hip/hip_runtime.h>
#include <stdint.h>

#define Bsz   16384
#define Xsz   50
#define CINsz 128
#define Hsz   128
#define BH    (Bsz * Hsz)

typedef __attribute__((ext_vector_type(8))) short short8;
typedef __attribute__((ext_vector_type(4))) float float4v;

__device__ __forceinline__ float bf2f(ushort u) {
    union { uint32_t i; float f; } v; v.i = ((uint32_t)u) << 16; return v.f;
}
__device__ __forceinline__ ushort f2bf(float f) {
    union { float f; uint32_t i; } v; v.f = f;
    uint32_t i = v.i;
    uint32_t r = (i + 0x7FFFu + ((i >> 16) & 1u)) >> 16;
    return (ushort)r;
}
__device__ __forceinline__ float fast_exp(float x) {       // e^x
    return __builtin_amdgcn_exp2f(x * 1.44269504f);
}
__device__ __forceinline__ float fast_rcp(float x) {
    return __builtin_amdgcn_rcpf(x);
}
__device__ __forceinline__ float fast_sigmoid(float x) {
    return fast_rcp(1.0f + __builtin_amdgcn_exp2f(-1.44269504f * x));
}
__device__ __forceinline__ float fast_tanh(float x) {
    float t = __builtin_amdgcn_exp2f(2.88539008f * x);
    return 1.0f - 2.0f * fast_rcp(t + 1.0f);
}

// ---------------------------------------------------------------------------
// Phase A (f32 in/out): per-b gate precompute.
//   gates = inp@Wih + h0@Whh + bias  -> i,o,g ; a_base = inp@aWih + abias
// Stores f32 to ws: [0]=e_i, [1]=g*e_i, [2]=sigmoid(o), [3]=a_base, each B*H.
// ---------------------------------------------------------------------------
__global__ __launch_bounds__(256) void phaseA_kernel(
    const float* __restrict__ inp, const float* __restrict__ h0,
    const float* __restrict__ Wih, const float* __restrict__ Whh,
    const float* __restrict__ bias, const float* __restrict__ aWih,
    const float* __restrict__ abias, float* __restrict__ ws)
{
    __shared__ float sIn[16][128];
    __shared__ float sH0[16][128];
    const int tid = threadIdx.x;
    const int b0 = blockIdx.x * 16;

    // stage inp/h0 tiles (coalesced, 32B per thread per array)
    {
        int row = tid >> 4;            // 0..15
        int col = (tid & 15) * 8;      // 0..120
        const float4* gi = (const float4*)(inp + (size_t)(b0 + row) * CINsz + col);
        const float4* gh = (const float4*)(h0 + (size_t)(b0 + row) * Hsz + col);
        *(float4*)&sIn[row][col]     = gi[0];
        *(float4*)&sIn[row][col + 4] = gi[1];
        *(float4*)&sH0[row][col]     = gh[0];
        *(float4*)&sH0[row][col + 4] = gh[1];
    }
    __syncthreads();

    const int h = tid & 127;
    const int bg = tid >> 7;           // 0..1

    float aI[8] = {}, aO[8] = {}, aG[8] = {}, aA[8] = {};

    for (int k0 = 0; k0 < CINsz; k0 += 4) {
        float wi[4], wo[4], wg[4], vi[4], vo[4], vg[4], wa[4];
#pragma unroll
        for (int kk = 0; kk < 4; ++kk) {
            int k = k0 + kk;
            wi[kk] = Wih[k * 384 + h];
            wo[kk] = Wih[k * 384 + h + 128];
            wg[kk] = Wih[k * 384 + h + 256];
            vi[kk] = Whh[k * 384 + h];
            vo[kk] = Whh[k * 384 + h + 128];
            vg[kk] = Whh[k * 384 + h + 256];
            wa[kk] = aWih[k * 128 + h];
        }
#pragma unroll
        for (int j = 0; j < 8; ++j) {
            int r = bg * 8 + j;
            float4 iv = *(const float4*)&sIn[r][k0];   // broadcast across lanes
            float4 hv = *(const float4*)&sH0[r][k0];
            float xin[4] = { iv.x, iv.y, iv.z, iv.w };
            float xh[4]  = { hv.x, hv.y, hv.z, hv.w };
#pragma unroll
            for (int kk = 0; kk < 4; ++kk) {
                aI[j] = fmaf(xin[kk], wi[kk], fmaf(xh[kk], vi[kk], aI[j]));
                aO[j] = fmaf(xin[kk], wo[kk], fmaf(xh[kk], vo[kk], aO[j]));
                aG[j] = fmaf(xin[kk], wg[kk], fmaf(xh[kk], vg[kk], aG[j]));
                aA[j] = fmaf(xin[kk], wa[kk], aA[j]);
            }
        }
    }

    const float bi  = bias[h];
    const float bo  = bias[h + 128];
    const float bg_ = bias[h + 256];
    const float ab  = abias[h];

    float* wsEI  = ws;
    float* wsGEI = ws + BH;
    float* wsO   = ws + 2 * (size_t)BH;
    float* wsAB  = ws + 3 * (size_t)BH;

#pragma unroll
    for (int j = 0; j < 8; ++j) {
        int b = b0 + bg * 8 + j;
        float i_s = fast_sigmoid(aI[j] + bi);
        float e_i = fast_exp(i_s);
        float g_t = fast_tanh(aG[j] + bg_);
        float o_s = fast_sigmoid(aO[j] + bo);
        size_t idx = (size_t)b * Hsz + h;
        wsEI[idx]  = e_i;
        wsGEI[idx] = g_t * e_i;
        wsO[idx]   = o_s;
        wsAB[idx]  = aA[j] + ab;
    }
}

// ---------------------------------------------------------------------------
// Main kernel (f32 skip_c, f32 out): per block = 16 batch rows, 4 waves.
// x-loop: stage skip tile (f32->bf16) -> MFMA vs aWhh (LDS-transposed bf16)
// -> fused sigmoid/exp/mask with denom/num accumulated in C-layout registers.
// ---------------------------------------------------------------------------
__global__ __launch_bounds__(256) void mainK_kernel(
    const float* __restrict__ skip_c, const int* __restrict__ skip_count,
    const float* __restrict__ aWhh, const float* __restrict__ ws,
    float* __restrict__ out)
{
    __shared__ ushort W2t[128][136];   // W2t[n][k] = bf16(aWhh[k][n]); pad +8
    __shared__ ushort skipS[16][136];  // [m][h] bf16, pad +8

    const int tid = threadIdx.x;
    const int b0 = blockIdx.x * 16;

    // stage aWhh transposed+converted (coalesced global read; once)
    {
        int kr = tid >> 4;             // 0..15
        int n0 = (tid & 15) * 8;       // 0..120
#pragma unroll
        for (int it = 0; it < 8; ++it) {
            int k = it * 16 + kr;
            const float4* src = (const float4*)(aWhh + (size_t)k * 128 + n0);
            float4 v0 = src[0], v1 = src[1];
            W2t[n0 + 0][k] = f2bf(v0.x);
            W2t[n0 + 1][k] = f2bf(v0.y);
            W2t[n0 + 2][k] = f2bf(v0.z);
            W2t[n0 + 3][k] = f2bf(v0.w);
            W2t[n0 + 4][k] = f2bf(v1.x);
            W2t[n0 + 5][k] = f2bf(v1.y);
            W2t[n0 + 6][k] = f2bf(v1.z);
            W2t[n0 + 7][k] = f2bf(v1.w);
        }
    }

    const float* wsEI  = ws;
    const float* wsGEI = ws + BH;
    const float* wsO   = ws + 2 * (size_t)BH;
    const float* wsAB  = ws + 3 * (size_t)BH;

    const int lane = tid & 63;
    const int wv   = tid >> 6;         // wave 0..3
    const int quad = lane >> 4;        // 0..3
    const int ln   = lane & 15;        // 0..15
    const int nw0  = wv * 32;          // this wave's N base (2 tiles of 16)

    // per-lane constants in C layout: row m = quad*4 + r, col n = nw0 + t*16 + ln
    float ab[2][4];
    int cnt[4];
#pragma unroll
    for (int r = 0; r < 4; ++r) {
        int m = quad * 4 + r;
        cnt[r] = skip_count[b0 + m];
#pragma unroll
        for (int t = 0; t < 2; ++t)
            ab[t][r] = wsAB[(size_t)(b0 + m) * Hsz + nw0 + t * 16 + ln];
    }

    float dn[2][4] = {};
    float nm[2][4] = {};

    __syncthreads();   // W2t ready

    const int srow = tid >> 4;
    const int scol = (tid & 15) * 8;
    const float* gsk = skip_c + ((size_t)(b0 + srow) * Xsz) * Hsz + scol;

    for (int x = 0; x < Xsz; ++x) {
        // stage this x's 16x128 skip tile, converting f32 -> bf16
        float4 v0 = *(const float4*)gsk;
        float4 v1 = *(const float4*)(gsk + 4);
        gsk += Hsz;
        ushort tmp[8];
        tmp[0] = f2bf(v0.x); tmp[1] = f2bf(v0.y); tmp[2] = f2bf(v0.z); tmp[3] = f2bf(v0.w);
        tmp[4] = f2bf(v1.x); tmp[5] = f2bf(v1.y); tmp[6] = f2bf(v1.z); tmp[7] = f2bf(v1.w);
        *(uint4*)&skipS[srow][scol] = *(uint4*)tmp;
        __syncthreads();

        // z[m][n] = sum_h skip[m][h] * aWhh[h][n]
        float4v z[2] = { {0.f,0.f,0.f,0.f}, {0.f,0.f,0.f,0.f} };
#pragma unroll
        for (int kk = 0; kk < 4; ++kk) {
            short8 af = *(const short8*)&skipS[ln][kk * 32 + quad * 8];
#pragma unroll
            for (int t = 0; t < 2; ++t) {
                short8 bf = *(const short8*)&W2t[nw0 + t * 16 + ln][kk * 32 + quad * 8];
                z[t] = __builtin_amdgcn_mfma_f32_16x16x32_bf16(af, bf, z[t], 0, 0, 0);
            }
        }

        // fused elementwise: alpha=sigmoid(z+a_base); e=exp(alpha)*mask; accumulate
#pragma unroll
        for (int t = 0; t < 2; ++t) {
#pragma unroll
            for (int r = 0; r < 4; ++r) {
                int m = quad * 4 + r;
                int n = nw0 + t * 16 + ln;
                float zf = z[t][r] + ab[t][r];
                float alpha = fast_sigmoid(zf);
                float sv = bf2f(skipS[m][n]);
                float e = (x < cnt[r]) ? fast_exp(alpha) : 0.0f;
                dn[t][r] += e;
                nm[t][r] = fmaf(sv, e, nm[t][r]);
            }
        }
        __syncthreads();   // protect skipS before next-iter staging
    }

    // epilogue: c1 = (g*e_i + num)/(e_i + denom); h1 = o * tanh(c1)  [f32 out]
#pragma unroll
    for (int t = 0; t < 2; ++t) {
#pragma unroll
        for (int r = 0; r < 4; ++r) {
            int m = quad * 4 + r;
            int n = nw0 + t * 16 + ln;
            size_t idx = (size_t)(b0 + m) * Hsz + n;
            float ei  = wsEI[idx];
            float gei = wsGEI[idx];
            float os  = wsO[idx];
            float c1 = (gei + nm[t][r]) * fast_rcp(ei + dn[t][r]);
            float h1 = os * fast_tanh(c1);
            out[idx] = h1;
            out[(size_t)BH + idx] = c1;
        }
    }
}

extern "C" void kernel_launch(void* const* d_in, const int* in_sizes, int n_in,
                              void* d_out, int out_size, void* d_ws, size_t ws_size,
                              hipStream_t stream) {
    const float* inp   = (const float*)d_in[0];
    const float* skip  = (const float*)d_in[1];
    const int*   cnt   = (const int*)d_in[2];
    const float* h0    = (const float*)d_in[3];
    // d_in[4] = c0 : unused by the reference
    const float* Wih   = (const float*)d_in[5];
    const float* Whh   = (const float*)d_in[6];
    const float* bias  = (const float*)d_in[7];
    const float* aWih  = (const float*)d_in[8];
    const float* aWhh  = (const float*)d_in[9];
    const float* abias = (const float*)d_in[10];
    float* ws = (float*)d_ws;            // needs 4 * B * H * 4 B = 32 MiB
    float* out = (float*)d_out;

    phaseA_kernel<<<Bsz / 16, 256, 0, stream>>>(inp, h0, Wih, Whh, bias, aWih, abias, ws);
    mainK_kernel<<<Bsz / 16, 256, 0, stream>>>(skip, cnt, aWhh, ws, out);
}